// Round 3
// baseline (1040.756 us; speedup 1.0000x reference)
//
#include <hip/hip_runtime.h>

// AttentionFusion on MI355X (gfx950). B=32, C=1024, HW=1024.
// All GEMMs 1024^3, bf16 MFMA fp32-acc, BM=BN=128, 4 waves.
// K-loop: BK=32, double-buffered LDS (2x16KB), ONE barrier per iteration --
// prefetch for k+1 issued right after the barrier publishing k, so the
// vmcnt(0) drain at the next barrier waits on loads issued a full iteration
// earlier (hides ~900cy HBM-miss latency that stalled the 2-barrier loop).
// LDS bank-conflict-free via XOR swizzle: phys colgroup = cg ^ (row&3).

typedef __bf16 bf16x8 __attribute__((ext_vector_type(8)));
typedef float floatx4 __attribute__((ext_vector_type(4)));

#define AS1(p) ((__attribute__((address_space(1))) void*)(p))
#define AS3(p) ((__attribute__((address_space(3))) void*)(p))

__device__ __forceinline__ unsigned short f2bf(float f) {
  union { float f; unsigned int u; } c; c.f = f;
  unsigned int u = c.u;
  u += 0x7fffu + ((u >> 16) & 1u);   // RNE to bf16
  return (unsigned short)(u >> 16);
}

// nan-free tanh: x->+inf: e^2x=inf -> 1-0=1;  x->-inf: e^2x=0 -> 1-2=-1
__device__ __forceinline__ float tanh_fast(float x) {
  float t = __expf(2.0f * x);
  return 1.0f - 2.0f / (t + 1.0f);
}

// ---------------------------------------------------------------------------
// Double-buffered GEMM core: acc[m][n] += sum_k A[m][k]*B[n][k], K=1024.
// lds layout (ushorts): [buf0: A 4096 | B 4096][buf1: A 4096 | B 4096]
// Stage chunk = 16 rows x 64B = 1KB = one global_load_lds_dwordx4 per wave.
// Lane l -> LDS (row=l>>2, physcg=l&3); source cg = (l&3) ^ (row&3).
// Reader frag (row, k=quad*8..): phys cg = quad ^ (row&3).
// ---------------------------------------------------------------------------
__device__ __forceinline__ void gemm_core(
    const unsigned short* __restrict__ Ab,
    const unsigned short* __restrict__ Bb,
    int m0, int n0,
    unsigned short* lds,
    floatx4 acc[4][4])
{
  constexpr int K = 1024;
  const int tid  = threadIdx.x;
  const int w    = tid >> 6;
  const int lane = tid & 63;
  const int quad = lane >> 4;
  const int lm   = lane & 15;
  const int wm   = (w >> 1) * 64;
  const int wn   = (w & 1) * 64;
  const int xr   = lm & 3;

  const int srow = lane >> 2;                  // 0..15 within chunk
  const int sg   = (lane & 3) ^ (srow & 3);    // swizzled source col-group
  const int q0   = w * 2;                      // this wave's first chunk

  const unsigned short* gA0 = Ab + (size_t)(m0 + q0 * 16 + srow) * K + sg * 8;
  const unsigned short* gA1 = gA0 + (size_t)16 * K;
  const unsigned short* gB0 = Bb + (size_t)(n0 + q0 * 16 + srow) * K + sg * 8;
  const unsigned short* gB1 = gB0 + (size_t)16 * K;

  unsigned short* dA0 = lds + q0 * 512;
  unsigned short* dB0 = lds + 4096 + q0 * 512;

  // prologue: stage k-chunk 0 into buf 0
  __builtin_amdgcn_global_load_lds(AS1(gA0), AS3(dA0),        16, 0, 0);
  __builtin_amdgcn_global_load_lds(AS1(gA1), AS3(dA0 + 512),  16, 0, 0);
  __builtin_amdgcn_global_load_lds(AS1(gB0), AS3(dB0),        16, 0, 0);
  __builtin_amdgcn_global_load_lds(AS1(gB1), AS3(dB0 + 512),  16, 0, 0);

  for (int k0 = 0; k0 < 32; ++k0) {
    __syncthreads();   // publishes buf[k0&1]; drains prefetch issued 1 iter ago

    if (k0 + 1 < 32) {
      const int kk = (k0 + 1) * 32;
      unsigned short* da = lds + ((k0 + 1) & 1) * 8192 + q0 * 512;
      unsigned short* db = da + 4096;
      __builtin_amdgcn_global_load_lds(AS1(gA0 + kk), AS3(da),       16, 0, 0);
      __builtin_amdgcn_global_load_lds(AS1(gA1 + kk), AS3(da + 512), 16, 0, 0);
      __builtin_amdgcn_global_load_lds(AS1(gB0 + kk), AS3(db),       16, 0, 0);
      __builtin_amdgcn_global_load_lds(AS1(gB1 + kk), AS3(db + 512), 16, 0, 0);
    }

    const unsigned short* la = lds + (k0 & 1) * 8192;
    const unsigned short* lb = la + 4096;

    bf16x8 af[4], bfv[4];
#pragma unroll
    for (int i = 0; i < 4; ++i) {
      const int row = wm + 16 * i + lm;
      af[i] = *(const bf16x8*)(la + row * 32 + ((quad ^ xr) * 8));
    }
#pragma unroll
    for (int j = 0; j < 4; ++j) {
      const int row = wn + 16 * j + lm;
      bfv[j] = *(const bf16x8*)(lb + row * 32 + ((quad ^ xr) * 8));
    }

#pragma unroll
    for (int i = 0; i < 4; ++i)
#pragma unroll
      for (int j = 0; j < 4; ++j)
        acc[i][j] = __builtin_amdgcn_mfma_f32_16x16x32_bf16(
            af[i], bfv[j], acc[i][j], 0, 0, 0);
  }
}

// ---------------------------------------------------------------------------
// Generic epilogue GEMM (templated): C = epi(scale * A.B^T)
// ---------------------------------------------------------------------------
template<int OUT_F32, int BIAS_MODE /*0 none,1 m,2 n*/, int TANH_ON, int RESID_ON>
__global__ __launch_bounds__(256, 2)
void gemm_bt(const unsigned short* __restrict__ A,
             const unsigned short* __restrict__ B,
             void* __restrict__ Cv,
             const float* __restrict__ bias,
             const float* __restrict__ resid,
             float scale,
             size_t sA, size_t sB, size_t sC, size_t sR)
{
  __shared__ unsigned short lds[16384];
  const int m0 = blockIdx.y * 128, n0 = blockIdx.x * 128;
  const int lane = threadIdx.x & 63, w = threadIdx.x >> 6;
  const int quad = lane >> 4, lm = lane & 15;
  const int wm = (w >> 1) * 64, wn = (w & 1) * 64;

  floatx4 acc[4][4];
#pragma unroll
  for (int i = 0; i < 4; ++i)
#pragma unroll
    for (int j = 0; j < 4; ++j) acc[i][j] = (floatx4)(0.0f);

  gemm_core(A + blockIdx.z * sA, B + blockIdx.z * sB, m0, n0, lds, acc);

  float* Cf = (float*)Cv + blockIdx.z * sC;
  unsigned short* Cb = (unsigned short*)Cv + blockIdx.z * sC;
  const float* rp = RESID_ON ? (resid + blockIdx.z * sR) : (const float*)0;

  // C/D mapping (verified): n = lane&15, m = quad*4 + reg
#pragma unroll
  for (int i = 0; i < 4; ++i) {
    const int mbase = m0 + wm + 16 * i + quad * 4;
#pragma unroll
    for (int j = 0; j < 4; ++j) {
      const int n = n0 + wn + 16 * j + lm;
#pragma unroll
      for (int r = 0; r < 4; ++r) {
        const int m = mbase + r;
        float val = acc[i][j][r] * scale;
        if (BIAS_MODE == 1) val += bias[m];
        if (BIAS_MODE == 2) val += bias[n];
        if (TANH_ON) val = tanh_fast(val);
        if (RESID_ON) val += rp[(size_t)m * 1024 + n];
        if (OUT_F32) Cf[(size_t)m * 1024 + n] = val;
        else         Cb[(size_t)m * 1024 + n] = f2bf(val);
      }
    }
  }
}

// ---------------------------------------------------------------------------
// Fused Q/K/V GEMM: z in [0,3*nb) selects op + batch.  All tanh, bf16 out.
// ---------------------------------------------------------------------------
__global__ __launch_bounds__(256, 2)
void qkv_gemm(const unsigned short* __restrict__ wqb,
              const unsigned short* __restrict__ wkb,
              const unsigned short* __restrict__ wvb,
              const unsigned short* __restrict__ Xt,
              const unsigned short* __restrict__ Yt,
              unsigned short* __restrict__ Qb,
              unsigned short* __restrict__ Kb,
              unsigned short* __restrict__ Vt,
              const float* __restrict__ bq,
              const float* __restrict__ bk,
              const float* __restrict__ bv,
              size_t sBf, int nb)
{
  __shared__ unsigned short lds[16384];
  const int z = blockIdx.z;
  int op, b;
  if (z >= 2 * nb)      { op = 2; b = z - 2 * nb; }
  else if (z >= nb)     { op = 1; b = z - nb; }
  else                  { op = 0; b = z; }

  const unsigned short *A, *B;
  unsigned short* C;
  const float* bias;
  int biasM;
  if (op == 0)      { A = wqb;          B = Xt + b * sBf; C = Qb + b * sBf; bias = bq; biasM = 1; }
  else if (op == 1) { A = wkb;          B = Yt + b * sBf; C = Kb + b * sBf; bias = bk; biasM = 1; }
  else              { A = Yt + b * sBf; B = wvb;          C = Vt + b * sBf; bias = bv; biasM = 0; }

  const int m0 = blockIdx.y * 128, n0 = blockIdx.x * 128;
  const int lane = threadIdx.x & 63, w = threadIdx.x >> 6;
  const int quad = lane >> 4, lm = lane & 15;
  const int wm = (w >> 1) * 64, wn = (w & 1) * 64;

  floatx4 acc[4][4];
#pragma unroll
  for (int i = 0; i < 4; ++i)
#pragma unroll
    for (int j = 0; j < 4; ++j) acc[i][j] = (floatx4)(0.0f);

  gemm_core(A, B, m0, n0, lds, acc);

#pragma unroll
  for (int i = 0; i < 4; ++i) {
    const int mbase = m0 + wm + 16 * i + quad * 4;
#pragma unroll
    for (int j = 0; j < 4; ++j) {
      const int n = n0 + wn + 16 * j + lm;
      const float bn = biasM ? 0.0f : bias[n];
#pragma unroll
      for (int r = 0; r < 4; ++r) {
        const int m = mbase + r;
        float val = acc[i][j][r] + (biasM ? bias[m] : bn);
        val = tanh_fast(val);
        C[(size_t)m * 1024 + n] = f2bf(val);
      }
    }
  }
}

// ---------------------------------------------------------------------------
// Dual transpose 1024x1024 fp32 -> bf16: z<nb: in0->out0, else in1->out1
// ---------------------------------------------------------------------------
__global__ __launch_bounds__(256)
void transpose2(const float* __restrict__ in0, const float* __restrict__ in1,
                unsigned short* __restrict__ out0, unsigned short* __restrict__ out1,
                size_t sIn, size_t sOut, int nb)
{
  __shared__ float tile[32][33];
  const int z = blockIdx.z;
  const float* in;
  unsigned short* out;
  if (z < nb) { in = in0 + (size_t)z * sIn;        out = out0 + (size_t)z * sOut; }
  else        { in = in1 + (size_t)(z - nb) * sIn; out = out1 + (size_t)(z - nb) * sOut; }

  const int x  = blockIdx.x * 32 + threadIdx.x;
  const int y0 = blockIdx.y * 32;
#pragma unroll
  for (int k = 0; k < 32; k += 8)
    tile[threadIdx.y + k][threadIdx.x] =
        in[(size_t)(y0 + threadIdx.y + k) * 1024 + x];
  __syncthreads();
  const int xo  = blockIdx.y * 32 + threadIdx.x;
  const int yo0 = blockIdx.x * 32;
#pragma unroll
  for (int k = 0; k < 32; k += 8)
    out[(size_t)(yo0 + threadIdx.y + k) * 1024 + xo] =
        f2bf(tile[threadIdx.x][threadIdx.y + k]);
}

// ---------------------------------------------------------------------------
// Row softmax: 1024 fp32 -> 1024 bf16, one block per row
// ---------------------------------------------------------------------------
__global__ __launch_bounds__(256)
void softmax_rows(const float* __restrict__ S, unsigned short* __restrict__ W,
                  size_t sS, size_t sW)
{
  const float* s = S + blockIdx.y * sS + (size_t)blockIdx.x * 1024;
  unsigned short* w = W + blockIdx.y * sW + (size_t)blockIdx.x * 1024;
  const int t = threadIdx.x;
  float4 v = ((const float4*)s)[t];
  float mx = fmaxf(fmaxf(v.x, v.y), fmaxf(v.z, v.w));
#pragma unroll
  for (int off = 32; off > 0; off >>= 1)
    mx = fmaxf(mx, __shfl_xor(mx, off));
  __shared__ float redm[4], reds[4];
  const int lane = t & 63, wv = t >> 6;
  if (lane == 0) redm[wv] = mx;
  __syncthreads();
  mx = fmaxf(fmaxf(redm[0], redm[1]), fmaxf(redm[2], redm[3]));
  float e0 = __expf(v.x - mx), e1 = __expf(v.y - mx),
        e2 = __expf(v.z - mx), e3 = __expf(v.w - mx);
  float sum = e0 + e1 + e2 + e3;
#pragma unroll
  for (int off = 32; off > 0; off >>= 1)
    sum += __shfl_xor(sum, off);
  if (lane == 0) reds[wv] = sum;
  __syncthreads();
  sum = reds[0] + reds[1] + reds[2] + reds[3];
  const float inv = 1.0f / sum;
  w[4 * t + 0] = f2bf(e0 * inv);
  w[4 * t + 1] = f2bf(e1 * inv);
  w[4 * t + 2] = f2bf(e2 * inv);
  w[4 * t + 3] = f2bf(e3 * inv);
}

// ---------------------------------------------------------------------------
// Convert all four 1024x1024 fp32 weights -> bf16 in one dispatch (y=op)
// ---------------------------------------------------------------------------
__global__ __launch_bounds__(256)
void cvt_all(const float* __restrict__ s0, const float* __restrict__ s1,
             const float* __restrict__ s2, const float* __restrict__ s3,
             unsigned short* __restrict__ d0, unsigned short* __restrict__ d1,
             unsigned short* __restrict__ d2, unsigned short* __restrict__ d3)
{
  const float* in; unsigned short* out;
  switch (blockIdx.y) {
    case 0: in = s0; out = d0; break;
    case 1: in = s1; out = d1; break;
    case 2: in = s2; out = d2; break;
    default: in = s3; out = d3; break;
  }
  const int i = blockIdx.x * 256 + threadIdx.x;
  float4 v = ((const float4*)in)[i];
  ushort4 o;
  o.x = f2bf(v.x); o.y = f2bf(v.y); o.z = f2bf(v.z); o.w = f2bf(v.w);
  ((ushort4*)out)[i] = o;
}

extern "C" void kernel_launch(void* const* d_in, const int* in_sizes, int n_in,
                              void* d_out, int out_size, void* d_ws, size_t ws_size,
                              hipStream_t stream)
{
  const float* shape_map = (const float*)d_in[0];
  const float* img_map   = (const float*)d_in[1];
  const float* wq = (const float*)d_in[2];
  const float* bq = (const float*)d_in[3];
  const float* wk = (const float*)d_in[4];
  const float* bk = (const float*)d_in[5];
  const float* wv = (const float*)d_in[6];
  const float* bv = (const float*)d_in[7];
  const float* wc = (const float*)d_in[8];
  const float* bc = (const float*)d_in[9];
  float* out = (float*)d_out;

  const size_t ELT = 1024 * 1024;
  const size_t MB  = 1024 * 1024;
  char* ws = (char*)d_ws;

  unsigned short* wq_b = (unsigned short*)(ws + 0 * 2 * MB);
  unsigned short* wk_b = (unsigned short*)(ws + 1 * 2 * MB);
  unsigned short* wv_b = (unsigned short*)(ws + 2 * 2 * MB);
  unsigned short* wc_b = (unsigned short*)(ws + 3 * 2 * MB);
  char* slots = ws + 8 * MB;
  const size_t slotBytes = 10 * MB;
  int nslots = (ws_size > 8 * MB + slotBytes)
                   ? (int)((ws_size - 8 * MB) / slotBytes) : 1;
  if (nslots > 32) nslots = 32;
  if (nslots < 1)  nslots = 1;

  cvt_all<<<dim3(1024, 4), 256, 0, stream>>>(wq, wk, wv, wc,
                                             wq_b, wk_b, wv_b, wc_b);

  const size_t sBf = slotBytes / 2;
  const size_t sF  = slotBytes / 4;

  for (int c0 = 0; c0 < 32; c0 += nslots) {
    const int nb = (32 - c0 < nslots) ? (32 - c0) : nslots;

    unsigned short* Xt  = (unsigned short*)(slots + 0);
    unsigned short* Yt  = (unsigned short*)(slots + 2 * MB);
    float*          Sm  = (float*)(slots + 0);
    unsigned short* Qb  = (unsigned short*)(slots + 4 * MB);
    unsigned short* Kb  = (unsigned short*)(slots + 6 * MB);
    unsigned short* Vt  = (unsigned short*)(slots + 8 * MB);
    unsigned short* Wsm = Qb;   // Q dead after scores
    unsigned short* NVt = Kb;   // K2 dead after scores

    transpose2<<<dim3(32, 32, 2 * nb), dim3(32, 8), 0, stream>>>(
        shape_map + (size_t)c0 * ELT, img_map + (size_t)c0 * ELT,
        Xt, Yt, ELT, sBf, nb);

    qkv_gemm<<<dim3(8, 8, 3 * nb), 256, 0, stream>>>(
        wq_b, wk_b, wv_b, Xt, Yt, Qb, Kb, Vt, bq, bk, bv, sBf, nb);

    gemm_bt<1, 0, 0, 0><<<dim3(8, 8, nb), 256, 0, stream>>>(
        Qb, Kb, Sm, nullptr, nullptr, 0.03125f, sBf, sBf, sF, 0);

    softmax_rows<<<dim3(1024, nb), 256, 0, stream>>>(Sm, Wsm, sF, sBf);

    gemm_bt<0, 0, 0, 0><<<dim3(8, 8, nb), 256, 0, stream>>>(
        Vt, Wsm, NVt, nullptr, nullptr, 1.0f, sBf, sBf, sBf, 0);

    gemm_bt<1, 1, 0, 1><<<dim3(8, 8, nb), 256, 0, stream>>>(
        wc_b, NVt, out + (size_t)c0 * ELT, bc,
        shape_map + (size_t)c0 * ELT, 1.0f, 0, sBf, ELT, ELT);
  }
}